// Round 2
// baseline (82.038 us; speedup 1.0000x reference)
//
#include <hip/hip_runtime.h>
#include <hip/hip_bf16.h>

#define B_SZ   1024
#define IN_F   256
#define OUT_F  256
#define NB     9            // 8 spline bases + 1 silu/base term
#define KTOT   (IN_F * NB)  // 2304
#define NGRID  12           // GRID_SIZE + 2K + 1

#define ICH    128          // i-values per K-chunk
#define KCH    (ICH * NB)   // 1152 k per chunk (layout k = i*9 + n)
#define STR    (KCH + 8)    // 1160 bf16 row stride: 2320 B, 16B-aligned,
                            // word-stride 580 ≡ 4 (mod 32) -> even bank load
#define NWAVE  12
#define THREADS 768
#define KSEG   (KCH / NWAVE) // 96 k per wave per chunk = 6 MFMA steps

typedef __attribute__((ext_vector_type(8))) short  bf16x8;
typedef __attribute__((ext_vector_type(16))) float f32x16;

__device__ __forceinline__ short f2bs(float v) {
  __hip_bfloat16 b = __float2bfloat16(v);
  return *reinterpret_cast<short*>(&b);
}

// ---------------------------------------------------------------------------
// Fully fused KAN layer: one kernel, no workspace.
// 256 blocks (32 bm-tiles fast × 8 bn-tiles) × 768 threads (12 waves).
// Per block: 32x32 C-tile. Two K-chunks (i in [0,128),[128,256)):
//   phase A: all threads compute spline bases + silu for (row, i) pairs of
//            the Phi tile straight into LDS (uniform-knot de Boor: 1 rcp).
//   phase B: all threads compute W = {sw*coeff | bw} tile into LDS.
//   sync; 12 waves MFMA disjoint 96-wide k-segments; sync.
// Reduce 12 partials in reused LDS (6 buffers, waves 6-11 add into 0-5).
// A/B frag (32x32x16): lane holds row (lane&31), k = (lane>>5)*8 + j.
// C/D (32x32): col = lane&31, row = (reg&3) + 8*(reg>>2) + 4*(lane>>5). [m74/m101]
// ---------------------------------------------------------------------------
__global__ __launch_bounds__(THREADS) void kan_fused(
    const float* __restrict__ x,
    const float* __restrict__ grid,
    const float* __restrict__ coeff,
    const float* __restrict__ bw,
    const float* __restrict__ sw,
    float* __restrict__ out) {
  __shared__ __align__(16) short smem[2 * 32 * STR];   // 148,480 B
  short* As = smem;
  short* Bs = smem + 32 * STR;

  int tid  = threadIdx.x;
  int wave = tid >> 6;          // 0..11
  int lane = tid & 63;
  int r = lane & 31;
  int h = lane >> 5;
  int bm = (blockIdx.x & 31) * 32;   // 32 b-tiles (fast index)
  int bn = (blockIdx.x >> 5) * 32;   // 8 o-tiles

  float g[NGRID];
#pragma unroll
  for (int j = 0; j < NGRID; ++j) g[j] = grid[j];
  // uniform spacing: all de Boor denominators are p*h (> 0, clip dead)
  float hh = g[1] - g[0];
  float r1 = __builtin_amdgcn_rcpf(hh);
  float rp[3] = { r1, 0.5f * r1, (1.0f / 3.0f) * r1 };

  f32x16 acc;
#pragma unroll
  for (int q = 0; q < 16; ++q) acc[q] = 0.0f;

  for (int c = 0; c < 2; ++c) {
    int i0 = c * ICH;

    // ---- Phi tile: 32 rows x 128 i -> As ----
    for (int p = tid; p < 32 * ICH; p += THREADS) {
      int row = p >> 7;         // ICH == 128
      int i   = p & (ICH - 1);
      float xv = x[(size_t)(bm + row) * IN_F + i0 + i];

      float bas[NGRID - 1];
#pragma unroll
      for (int j = 0; j < NGRID - 1; ++j)
        bas[j] = (xv >= g[j] && xv < g[j + 1]) ? 1.0f : 0.0f;
#pragma unroll
      for (int p3 = 1; p3 <= 3; ++p3) {
        int n = NGRID - 1 - p3;
        float inv = rp[p3 - 1];
#pragma unroll
        for (int j = 0; j < n; ++j)
          bas[j] = ((xv - g[j]) * bas[j] + (g[p3 + 1 + j] - xv) * bas[j + 1]) * inv;
      }
      bas[7] += (xv >= g[NGRID - 4]) ? 1.0f : 0.0f;
      float sil = xv / (1.0f + __expf(-xv));

      short* d = As + row * STR + i * NB;
#pragma unroll
      for (int n = 0; n < 8; ++n) d[n] = f2bs(bas[n]);
      d[8] = f2bs(sil);
    }

    // ---- W tile: 32 o-rows x 128 i -> Bs ----
    for (int p = tid; p < 32 * ICH; p += THREADS) {
      int o = p >> 7;
      int i = p & (ICH - 1);
      int gi = (bn + o) * IN_F + i0 + i;
      float s = sw[gi];
      const float4* c4 = (const float4*)(coeff + (size_t)gi * 8);
      float4 c0 = c4[0];
      float4 c1 = c4[1];
      short* d = Bs + o * STR + i * NB;
      d[0] = f2bs(s * c0.x);
      d[1] = f2bs(s * c0.y);
      d[2] = f2bs(s * c0.z);
      d[3] = f2bs(s * c0.w);
      d[4] = f2bs(s * c1.x);
      d[5] = f2bs(s * c1.y);
      d[6] = f2bs(s * c1.z);
      d[7] = f2bs(s * c1.w);
      d[8] = f2bs(bw[gi]);
    }
    __syncthreads();

    // ---- MFMA: wave w owns k-segment [w*96, w*96+96) of this chunk ----
    const short* ap = As + r * STR + wave * KSEG + h * 8;
    const short* bp = Bs + r * STR + wave * KSEG + h * 8;
#pragma unroll
    for (int k = 0; k < KSEG; k += 16) {
      bf16x8 a = *(const bf16x8*)(ap + k);
      bf16x8 b = *(const bf16x8*)(bp + k);
      acc = __builtin_amdgcn_mfma_f32_32x32x16_bf16(a, b, acc, 0, 0, 0);
    }
    __syncthreads();
  }

  // ---- reduce 12 wave-partials (reuse LDS: 6 buffers x 1024 f32) ----
  float* partial = (float*)smem;
  float* pw = partial + (wave % 6) * 1024;
  if (wave < 6) {
#pragma unroll
    for (int q = 0; q < 16; ++q) {
      int crow = (q & 3) + 8 * (q >> 2) + 4 * h;
      pw[crow * 32 + r] = acc[q];   // lanes 0..31 -> banks 0..31
    }
  }
  __syncthreads();
  if (wave >= 6) {
#pragma unroll
    for (int q = 0; q < 16; ++q) {
      int crow = (q & 3) + 8 * (q >> 2) + 4 * h;
      pw[crow * 32 + r] += acc[q];  // each buffer: exactly one adding wave
    }
  }
  __syncthreads();

  for (int e = tid; e < 1024; e += THREADS) {
    float s = 0.0f;
#pragma unroll
    for (int w = 0; w < 6; ++w) s += partial[w * 1024 + e];
    out[(size_t)(bm + (e >> 5)) * OUT_F + bn + (e & 31)] = s;
  }
}

// ---------------------------------------------------------------------------
extern "C" void kernel_launch(void* const* d_in, const int* in_sizes, int n_in,
                              void* d_out, int out_size, void* d_ws, size_t ws_size,
                              hipStream_t stream) {
  const float* x     = (const float*)d_in[0];
  const float* grid  = (const float*)d_in[1];
  const float* coeff = (const float*)d_in[2];
  const float* bw    = (const float*)d_in[3];
  const float* sw    = (const float*)d_in[4];
  float* out = (float*)d_out;
  (void)d_ws; (void)ws_size;

  kan_fused<<<(B_SZ / 32) * (OUT_F / 32), THREADS, 0, stream>>>(
      x, grid, coeff, bw, sw, out);
}

// Round 3
// 75.255 us; speedup vs baseline: 1.0901x; 1.0901x over previous
//
#include <hip/hip_runtime.h>
#include <hip/hip_bf16.h>

#define B_SZ   1024
#define IN_F   256
#define OUT_F  256
#define NB     9            // 8 spline bases + 1 silu/base term
#define KTOT   (IN_F * NB)  // 2304
#define NGRID  12           // GRID_SIZE + 2K + 1

typedef __attribute__((ext_vector_type(8))) short  bf16x8;
typedef __attribute__((ext_vector_type(16))) float f32x16;

// ---------------------------------------------------------------------------
// Prep kernel (fused): blocks [0,1024) build Phi, blocks [1024,1280) build W.
// Phi[b][k], k = n*256 + i : 8 cubic B-spline bases (+edge fixup) and silu(x).
// W[o][k],  k = n*256 + i : n<8 -> sw*coeff ; n==8 -> bw.   Both bf16.
// Uniform-knot: g[p+j]-g[j] == p*h exactly => ONE rcp(h), denominators
// hoisted. NOTE: numerics kept bit-identical to the 75.35 µs round-1 version.
// ---------------------------------------------------------------------------
__global__ __launch_bounds__(256) void kan_prep(
    const float* __restrict__ x,
    const float* __restrict__ grid,
    const float* __restrict__ coeff,
    const float* __restrict__ bw,
    const float* __restrict__ sw,
    __hip_bfloat16* __restrict__ phi,
    __hip_bfloat16* __restrict__ W) {
  if (blockIdx.x < (B_SZ * IN_F) / 256) {
    // ---- features ----
    int idx = blockIdx.x * 256 + threadIdx.x;   // 0 .. B*IN_F-1
    float g[NGRID];
#pragma unroll
    for (int j = 0; j < NGRID; ++j) g[j] = grid[j];
    float xv = x[idx];

    float bas[NGRID - 1];
#pragma unroll
    for (int j = 0; j < NGRID - 1; ++j)
      bas[j] = (xv >= g[j] && xv < g[j + 1]) ? 1.0f : 0.0f;

    float h = g[1] - g[0];
    float r1 = __builtin_amdgcn_rcpf(h);
    float rp[3] = { r1, 0.5f * r1, (1.0f / 3.0f) * r1 };

#pragma unroll
    for (int p = 1; p <= 3; ++p) {
      int n = NGRID - 1 - p;
      float inv = rp[p - 1];
#pragma unroll
      for (int j = 0; j < n; ++j) {
        bas[j] = ((xv - g[j]) * bas[j] + (g[p + 1 + j] - xv) * bas[j + 1]) * inv;
      }
    }
    bas[7] += (xv >= g[NGRID - 4]) ? 1.0f : 0.0f;
    float sil = xv / (1.0f + __expf(-xv));

    int b = idx >> 8;
    int i = idx & 255;
    __hip_bfloat16* dst = phi + (size_t)b * KTOT + i;
#pragma unroll
    for (int n = 0; n < 8; ++n) dst[n * IN_F] = __float2bfloat16(bas[n]);
    dst[8 * IN_F] = __float2bfloat16(sil);
  } else {
    // ---- weights ----
    int idx = (blockIdx.x - (B_SZ * IN_F) / 256) * 256 + threadIdx.x;  // 0..65535
    int o = idx >> 8;
    int i = idx & 255;
    float s = sw[idx];
    const float4* c4 = (const float4*)(coeff + (size_t)idx * 8);
    float4 c0 = c4[0];
    float4 c1 = c4[1];
    __hip_bfloat16* dst = W + (size_t)o * KTOT + i;
    dst[0 * IN_F] = __float2bfloat16(s * c0.x);
    dst[1 * IN_F] = __float2bfloat16(s * c0.y);
    dst[2 * IN_F] = __float2bfloat16(s * c0.z);
    dst[3 * IN_F] = __float2bfloat16(s * c0.w);
    dst[4 * IN_F] = __float2bfloat16(s * c1.x);
    dst[5 * IN_F] = __float2bfloat16(s * c1.y);
    dst[6 * IN_F] = __float2bfloat16(s * c1.z);
    dst[7 * IN_F] = __float2bfloat16(s * c1.w);
    dst[8 * IN_F] = __float2bfloat16(bw[idx]);
  }
}

// ---------------------------------------------------------------------------
// GEMM: C[1024x256] = Phi · W^T, K=2304, bf16 in / f32 out.
// 256 blocks × 1024 threads (16 waves, 4/SIMD). Each block owns one 32x32
// C-tile; its 16 waves split K (144 each). K-loop FULLY unrolled: all 18
// bf16x8 loads issue before the acc-chained MFMAs consume them -> one L2/L3
// latency exposure (~500 cy) instead of three (was #pragma unroll 3).
// Reduce: 16 partial buffers (64 KB LDS, 1 block/CU so no occupancy cost),
// ONE barrier, 1024 threads × 16-way sum (2-way LDS aliasing = free).
// A/B frag (32x32x16): lane holds row (lane&31), k = (lane>>5)*8 + j.
// C/D (32x32): col = lane&31, row = (reg&3) + 8*(reg>>2) + 4*(lane>>5). [m74/m101]
// Block mapping: bm fast index -> each XCD (blockIdx%8 r-r) touches only
// 4 phi strips + W => L2-resident per XCD.
// ---------------------------------------------------------------------------
#define KSEG (KTOT / 16)   // 144 per wave = 9 MFMA steps

__global__ __launch_bounds__(1024, 4) void kan_gemm(
    const __hip_bfloat16* __restrict__ phi,
    const __hip_bfloat16* __restrict__ W,
    float* __restrict__ out) {
  __shared__ float partial[16][32 * 32];   // 64 KB

  int tid  = threadIdx.x;
  int wave = tid >> 6;          // 0..15
  int lane = tid & 63;
  int bm = (blockIdx.x & 31) * 32;   // 32 b-tiles (fast index)
  int bn = (blockIdx.x >> 5) * 32;   // 8 o-tiles
  int r = lane & 31;
  int h = lane >> 5;            // half-wave

  const short* ap = (const short*)(phi + (size_t)(bm + r) * KTOT) + wave * KSEG + h * 8;
  const short* bp = (const short*)(W   + (size_t)(bn + r) * KTOT) + wave * KSEG + h * 8;

  f32x16 acc;
#pragma unroll
  for (int g = 0; g < 16; ++g) acc[g] = 0.0f;

#pragma unroll
  for (int k = 0; k < KSEG; k += 16) {
    bf16x8 a = *(const bf16x8*)(ap + k);
    bf16x8 b = *(const bf16x8*)(bp + k);
    acc = __builtin_amdgcn_mfma_f32_32x32x16_bf16(a, b, acc, 0, 0, 0);
  }

  float* pw = &partial[wave][0];
#pragma unroll
  for (int g = 0; g < 16; ++g) {
    int row = (g & 3) + 8 * (g >> 2) + 4 * h;
    pw[row * 32 + r] = acc[g];   // lanes 0..31 -> banks 0..31: conflict-free
  }
  __syncthreads();

  // final 16-way sum: 1024 threads × 1 element each
  float s = 0.0f;
#pragma unroll
  for (int w = 0; w < 16; ++w) s += partial[w][tid];
  int row = tid >> 5, col = tid & 31;
  out[(size_t)(bm + row) * OUT_F + bn + col] = s;
}

// ---------------------------------------------------------------------------
extern "C" void kernel_launch(void* const* d_in, const int* in_sizes, int n_in,
                              void* d_out, int out_size, void* d_ws, size_t ws_size,
                              hipStream_t stream) {
  const float* x     = (const float*)d_in[0];
  const float* grid  = (const float*)d_in[1];
  const float* coeff = (const float*)d_in[2];
  const float* bw    = (const float*)d_in[3];
  const float* sw    = (const float*)d_in[4];
  float* out = (float*)d_out;

  __hip_bfloat16* phi = (__hip_bfloat16*)d_ws;            // 1024*2304 bf16 = 4.5 MiB
  __hip_bfloat16* W   = phi + (size_t)B_SZ * KTOT;        // 256*2304 bf16 = 1.125 MiB

  kan_prep<<<(B_SZ * IN_F + OUT_F * IN_F) / 256, 256, 0, stream>>>(
      x, grid, coeff, bw, sw, phi, W);
  kan_gemm<<<(B_SZ / 32) * (OUT_F / 32), 1024, 0, stream>>>(phi, W, out);
}